// Round 9
// baseline (74.632 us; speedup 1.0000x reference)
//
#include <hip/hip_runtime.h>

#define NQ 12
#define NL 4
#define DIM 4096
#define BLOCK 512
#define PER_T 8           // amplitudes per thread, bits 6..8 of index
#define BATCH 256

// Index layout: j = lane | (k<<6) | (wv<<9)
//   bits 0..5  = lane (64) -> qubits 6..11 (shfl/DPP RY gates)
//   bits 6..8  = reg k (8) -> qubits 5,4,3  (register RY gates)
//   bits 9..11 = wave (8)  -> qubits 2,1,0  (ONE 8-pt LDS gather + CX perm)
// Qubit q lives at bit position 11-q.
// Layer = (encoding diag) (all RYs) (all RZs) (CX perm); RZ(q) after RY(q).
// RZs for q3..11 fuse into one per-amplitude diagonal; q0..2 RZs live in the
// gather coefficients. One barrier per layer via sP/sQ ping-pong.

__device__ __forceinline__ float2 cmul(float2 a, float2 b) {
    return make_float2(a.x * b.x - a.y * b.y, a.x * b.y + a.y * b.x);
}
__device__ __forceinline__ float2 cconj(float2 a) { return make_float2(a.x, -a.y); }

// HW sincos (revolutions + fract reduce); |err| ~1e-6 << 1.37e-2 threshold.
__device__ __forceinline__ float2 fsincos(float ang) {   // (cos, sin)
    float r = ang * 0.15915494309189535f;
    r = r - floorf(r);
    return make_float2(__builtin_amdgcn_cosf(r), __builtin_amdgcn_sinf(r));
}

// ---- lane exchanges: DPP for xor1/2/8, shfl for xor4/16/32 ----------------
template <int CTRL>
__device__ __forceinline__ float dppx(float v) {
    int i = __builtin_bit_cast(int, v);
    int r = __builtin_amdgcn_update_dpp(0, i, CTRL, 0xF, 0xF, true);
    return __builtin_bit_cast(float, r);
}
template <int MSK, int CTRL>
__device__ __forceinline__ void ry_dpp(float2* psi, int lane, float c, float s) {
    const float se = (lane & MSK) ? s : -s;
#pragma unroll
    for (int k = 0; k < PER_T; ++k) {
        float px = dppx<CTRL>(psi[k].x);
        float py = dppx<CTRL>(psi[k].y);
        psi[k].x = c * psi[k].x + se * px;
        psi[k].y = c * psi[k].y + se * py;
    }
}
template <int MSK>
__device__ __forceinline__ void ry_shfl(float2* psi, int lane, float c, float s) {
    const float se = (lane & MSK) ? s : -s;
#pragma unroll
    for (int k = 0; k < PER_T; ++k) {
        float px = __shfl_xor(psi[k].x, MSK, 64);
        float py = __shfl_xor(psi[k].y, MSK, 64);
        psi[k].x = c * psi[k].x + se * px;
        psi[k].y = c * psi[k].y + se * py;
    }
}

__global__ __launch_bounds__(BLOCK, 2) void qcp_kernel(
    const float* __restrict__ x,      // (BATCH, NQ)
    const float* __restrict__ w,      // (NL, NQ, 2) flat: [ry, rz] -> 96
    float* __restrict__ out)          // (BATCH,)
{
    __shared__ float2 sP[DIM];
    __shared__ float2 sQ[DIM];
    __shared__ float2 trig[NL * NQ * 2];   // (cos, sin) of 0.5*w[idx]
    __shared__ float  zhalf[NL * NQ];      // 0.5 * rz weight
    __shared__ float  rbuf[8];

    const int b    = blockIdx.x;
    const int t    = threadIdx.x;
    const int lane = t & 63;
    const int wv   = t >> 6;               // 0..7

    if (t < NL * NQ * 2) trig[t] = fsincos(0.5f * w[t]);
    if (t < NL * NQ) zhalf[t] = 0.5f * w[2 * t + 1];

    float xr[NQ];
#pragma unroll
    for (int q = 0; q < NQ; ++q) xr[q] = x[b * NQ + q];

    // Data-encoding phasors (identical each layer).
    float2 eph[PER_T];
#pragma unroll
    for (int k = 0; k < PER_T; ++k) {
        int j = lane | (k << 6) | (wv << 9);
        float ang = 0.0f;
#pragma unroll
        for (int q = 0; q < NQ; ++q)
            ang += ((j >> (NQ - 1 - q)) & 1) ? 0.5f * xr[q] : -0.5f * xr[q];
        eph[k] = fsincos(ang);
    }

    float2 psi[PER_T];
#pragma unroll
    for (int k = 0; k < PER_T; ++k) psi[k] = make_float2(0.015625f, 0.0f);

    __syncthreads();   // trig/zhalf ready

    for (int l = 0; l < NL; ++l) {
        // ---- 0) batched layer coefficients ---------------------------------
        float2 tRY[9];      // RY (c,s) for q=3..11
        float2 tE[3][2];    // q=0..2: RY(c,s), RZ(c,s)
        float  zh[6];       // 0.5*rz for q=6..11
        float2 z3, z4, z5;  // e^{i*0.5*rz} for reg qubits
#pragma unroll
        for (int q = 3; q <= 11; ++q) tRY[q - 3] = trig[(l * NQ + q) * 2];
#pragma unroll
        for (int q = 0; q < 3; ++q) {
            tE[q][0] = trig[(l * NQ + q) * 2 + 0];
            tE[q][1] = trig[(l * NQ + q) * 2 + 1];
        }
        z3 = trig[(l * NQ + 3) * 2 + 1];
        z4 = trig[(l * NQ + 4) * 2 + 1];
        z5 = trig[(l * NQ + 5) * 2 + 1];
#pragma unroll
        for (int q = 6; q <= 11; ++q) zh[q - 6] = zhalf[l * NQ + q];

        // ---- 1) diagonal data-encoding phase -------------------------------
#pragma unroll
        for (int k = 0; k < PER_T; ++k) psi[k] = cmul(psi[k], eph[k]);

        // ---- 2) register-bit RY gates: qubits 3..5 (k bit 5-q... = 11-q-6) -
#pragma unroll
        for (int q = 3; q <= 5; ++q) {
            const int kb = 5 - (q - 3) - (q - 3) ? 0 : 0;  // placeholder
            (void)kb;
        }
#pragma unroll
        for (int q = 3; q <= 5; ++q) {
            const int kbit = (11 - q) - 6;     // q3->2, q4->1, q5->0
            float c = tRY[q - 3].x, s = tRY[q - 3].y;
#pragma unroll
            for (int m = 0; m < PER_T / 2; ++m) {
                int k0 = ((m >> kbit) << (kbit + 1)) | (m & ((1 << kbit) - 1));
                int k1 = k0 | (1 << kbit);
                float2 a0 = psi[k0], a1 = psi[k1];
                psi[k0] = make_float2(c * a0.x - s * a1.x, c * a0.y - s * a1.y);
                psi[k1] = make_float2(s * a0.x + c * a1.x, s * a0.y + c * a1.y);
            }
        }

        // ---- 3) lane-bit RY gates: qubits 6..11 ----------------------------
        ry_shfl<32>(psi, lane, tRY[3].x, tRY[3].y);      // q6  xor32
        ry_shfl<16>(psi, lane, tRY[4].x, tRY[4].y);      // q7  xor16
        ry_dpp<8, 0x128>(psi, lane, tRY[5].x, tRY[5].y); // q8  xor8
        ry_shfl<4>(psi, lane, tRY[6].x, tRY[6].y);       // q9  xor4
        ry_dpp<2, 0x4E>(psi, lane, tRY[7].x, tRY[7].y);  // q10 xor2
        ry_dpp<1, 0xB1>(psi, lane, tRY[8].x, tRY[8].y);  // q11 xor1

        // ---- 4) fused RZ diagonal for qubits 3..11 -------------------------
        // angle = s_lane(q6..11) + (±zh3 ±zh4 ±zh5 by k bits 2,1,0)
        float s_lane = 0.0f;
#pragma unroll
        for (int p = 0; p < 6; ++p)          // lane bit p -> qubit 11-p -> zh[5-p]
            s_lane += ((lane >> p) & 1) ? zh[5 - p] : -zh[5 - p];
        {
            float2 base = fsincos(s_lane);
            float2 z45[4];
#pragma unroll
            for (int c2 = 0; c2 < 4; ++c2) {
                float2 a4 = (c2 & 2) ? z4 : cconj(z4);
                float2 a5 = (c2 & 1) ? z5 : cconj(z5);
                z45[c2] = cmul(a4, a5);
            }
#pragma unroll
            for (int k = 0; k < PER_T; ++k) {
                float2 a3 = (k & 4) ? z3 : cconj(z3);
                float2 ph = cmul(cmul(base, a3), z45[k & 3]);
                psi[k] = cmul(psi[k], ph);
            }
        }

        // ---- 5) wave-bit gates (qubits 0..2, RY+RZ) + CX perm: ONE gather --
        // out[j] = sum_{c<8} coef[c] * staged[(g&0x1FF) | (c<<9)], g=j^(j>>1)
        // rows (wave-uniform): q0: g11=j11; q1: g10=j10^j11; q2: g9=j9^j10
        float2 E[3][2];
        {
            const int rr[3] = { (wv >> 2) & 1,
                                ((wv >> 1) ^ (wv >> 2)) & 1,
                                (wv ^ (wv >> 1)) & 1 };
#pragma unroll
            for (int q = 0; q < 3; ++q) {
                float2 tr = tE[q][0];
                float2 tz = tE[q][1];
                int r = rr[q];
                float e0 = r ? tr.y : tr.x;
                float e1 = r ? tr.x : -tr.y;
                float2 ph = make_float2(tz.x, r ? tz.y : -tz.y);
                E[q][0] = make_float2(e0 * ph.x, e0 * ph.y);
                E[q][1] = make_float2(e1 * ph.x, e1 * ph.y);
            }
        }
        float2 coef[8];
#pragma unroll
        for (int c = 0; c < 8; ++c)   // c bit0->bit9 (q2 col), bit1->q1, bit2->q0
            coef[c] = cmul(cmul(E[0][(c >> 2) & 1], E[1][(c >> 1) & 1]), E[2][c & 1]);

        float2* buf = (l & 1) ? sQ : sP;
#pragma unroll
        for (int k = 0; k < PER_T; ++k) {
            int j = lane | (k << 6) | (wv << 9);
            buf[j] = psi[k];
        }
        __syncthreads();
#pragma unroll
        for (int k = 0; k < PER_T; ++k) {
            int j = lane | (k << 6) | (wv << 9);
            int g = j ^ (j >> 1);
            int base = g & 0x1FF;
            float2 r = make_float2(0.0f, 0.0f);
#pragma unroll
            for (int c = 0; c < 8; ++c) {
                float2 v = buf[base | (c << 9)];
                r.x += coef[c].x * v.x - coef[c].y * v.y;
                r.y += coef[c].x * v.y + coef[c].y * v.x;
            }
            psi[k] = r;
        }
        // No trailing barrier: reads of this buffer precede the NEXT layer's
        // barrier; the same buffer is rewritten two layers later, after it.
    }

    // ---- <Z(0)>: qubit 0 = bit 11 = wave bit 2 ----------------------------
    float acc = 0.0f;
#pragma unroll
    for (int k = 0; k < PER_T; ++k)
        acc += psi[k].x * psi[k].x + psi[k].y * psi[k].y;
    if (wv >= 4) acc = -acc;
#pragma unroll
    for (int off = 32; off > 0; off >>= 1)
        acc += __shfl_down(acc, off, 64);
    if (lane == 0) rbuf[wv] = acc;
    __syncthreads();
    if (t == 0) {
        float tot = 0.0f;
#pragma unroll
        for (int i = 0; i < 8; ++i) tot += rbuf[i];
        out[b] = tot;
    }
}

extern "C" void kernel_launch(void* const* d_in, const int* in_sizes, int n_in,
                              void* d_out, int out_size, void* d_ws, size_t ws_size,
                              hipStream_t stream) {
    const float* x = (const float*)d_in[0];   // (256, 12)
    const float* w = (const float*)d_in[1];   // (96,)
    float* out = (float*)d_out;               // (256, 1)
    qcp_kernel<<<BATCH, BLOCK, 0, stream>>>(x, w, out);
}

// Round 11
// 70.911 us; speedup vs baseline: 1.0525x; 1.0525x over previous
//
#include <hip/hip_runtime.h>

#define NQ 12
#define NL 4
#define DIM 4096
#define BLOCK 512
#define PER_T 8           // amplitudes per thread
#define BATCH 256

// Layout A: i = lane | k<<6 | wv<<9   (lane bits: q6-11, k: q3-5, wv: q0-2)
// Layout B: i = lane | wv<<6 | k<<9   (lane bits: q6-11, wv: q3-5, k: q0-2)
// Qubit q lives at bit position 11-q of the global amplitude index i.
//
// Per layer: encoding diag + RY(q3..11) + fused RZ(q3..11) in layout A;
//  pass1 (LDS): stage at own index, read layout-B set -> q0-2 on k bits;
//  RY+RZ(q0..2) as register butterflies;
//  pass2 (LDS): stage at own index, read at g = j^(j>>1) -> CX ladder is
//  pure addressing (no arithmetic), landing back in layout A.
// Lane exchanges: shfl for xor4/16/32, DPP intrinsics for xor1/2/8 — the
// exact primitive set that passed R6/R7/R8. (Permlane-swap inline asm is
// banned: two silent-corruption failures, zero measured upside.)

__device__ __forceinline__ float2 cmul(float2 a, float2 b) {
    return make_float2(a.x * b.x - a.y * b.y, a.x * b.y + a.y * b.x);
}
__device__ __forceinline__ float2 cconj(float2 a) { return make_float2(a.x, -a.y); }

// HW sincos (revolutions, fract-reduced); |err| ~1e-6 << 1.37e-2 threshold.
__device__ __forceinline__ float2 fsincos(float ang) {   // (cos, sin)
    float r = ang * 0.15915494309189535f;
    r = r - floorf(r);
    return make_float2(__builtin_amdgcn_cosf(r), __builtin_amdgcn_sinf(r));
}

// ---- lane exchanges -------------------------------------------------------
// DPP: quad_perm xor1 = 0xB1, xor2 = 0x4E; row_ror:8 = xor8 = 0x128.
template <int CTRL>
__device__ __forceinline__ float dppx(float v) {
    int i = __builtin_bit_cast(int, v);
    int r = __builtin_amdgcn_update_dpp(0, i, CTRL, 0xF, 0xF, true);
    return __builtin_bit_cast(float, r);
}
template <int MSK, int CTRL>
__device__ __forceinline__ void ry_dpp(float2* psi, int lane, float c, float s) {
    const float se = (lane & MSK) ? s : -s;
#pragma unroll
    for (int k = 0; k < PER_T; ++k) {
        float px = dppx<CTRL>(psi[k].x);
        float py = dppx<CTRL>(psi[k].y);
        psi[k].x = c * psi[k].x + se * px;
        psi[k].y = c * psi[k].y + se * py;
    }
}
template <int MSK>
__device__ __forceinline__ void ry_shfl(float2* psi, int lane, float c, float s) {
    const float se = (lane & MSK) ? s : -s;
#pragma unroll
    for (int k = 0; k < PER_T; ++k) {
        float px = __shfl_xor(psi[k].x, MSK, 64);
        float py = __shfl_xor(psi[k].y, MSK, 64);
        psi[k].x = c * psi[k].x + se * px;
        psi[k].y = c * psi[k].y + se * py;
    }
}

__global__ __launch_bounds__(BLOCK, 2) void qcp_kernel(
    const float* __restrict__ x,      // (BATCH, NQ)
    const float* __restrict__ w,      // (NL, NQ, 2) flat: [ry, rz] -> 96
    float* __restrict__ out)          // (BATCH,)
{
    __shared__ float2 sP[DIM];             // pass-1 staging
    __shared__ float2 sQ[DIM];             // pass-2 staging
    __shared__ float2 trig[NL * NQ * 2];   // (cos, sin) of 0.5*w[idx]
    __shared__ float  zhalf[NL * NQ];      // 0.5 * rz weight
    __shared__ float  rbuf[8];

    const int b    = blockIdx.x;
    const int t    = threadIdx.x;
    const int lane = t & 63;
    const int wv   = t >> 6;               // 0..7

    if (t < NL * NQ * 2) trig[t] = fsincos(0.5f * w[t]);
    if (t < NL * NQ) zhalf[t] = 0.5f * w[2 * t + 1];

    float xr[NQ];
#pragma unroll
    for (int q = 0; q < NQ; ++q) xr[q] = x[b * NQ + q];

    // Thread-constant addresses.
    int iA[PER_T], iB[PER_T], gI[PER_T];
#pragma unroll
    for (int k = 0; k < PER_T; ++k) {
        iA[k] = lane | (k << 6) | (wv << 9);
        iB[k] = lane | (wv << 6) | (k << 9);
        gI[k] = iA[k] ^ (iA[k] >> 1);
    }

    // Data-encoding phasors for the layout-A amp set (identical each layer).
    float2 eph[PER_T];
#pragma unroll
    for (int k = 0; k < PER_T; ++k) {
        int j = iA[k];
        float ang = 0.0f;
#pragma unroll
        for (int q = 0; q < NQ; ++q)
            ang += ((j >> (NQ - 1 - q)) & 1) ? 0.5f * xr[q] : -0.5f * xr[q];
        eph[k] = fsincos(ang);
    }

    float2 psi[PER_T];
#pragma unroll
    for (int k = 0; k < PER_T; ++k) psi[k] = make_float2(0.015625f, 0.0f);

    __syncthreads();   // trig/zhalf ready

    for (int l = 0; l < NL; ++l) {
        // ---- 0) layer coefficients -----------------------------------------
        float2 tRY[9];          // RY (c,s) for q=3..11
        float2 tRY0[3], tZ0[3]; // q=0..2 RY and RZ pairs
        float  zh[6];           // 0.5*rz for q=6..11
        float2 z3, z4, z5;      // e^{i*0.5*rz} for q=3..5
#pragma unroll
        for (int q = 3; q <= 11; ++q) tRY[q - 3] = trig[(l * NQ + q) * 2];
#pragma unroll
        for (int q = 0; q < 3; ++q) {
            tRY0[q] = trig[(l * NQ + q) * 2 + 0];
            tZ0[q]  = trig[(l * NQ + q) * 2 + 1];
        }
        z3 = trig[(l * NQ + 3) * 2 + 1];
        z4 = trig[(l * NQ + 4) * 2 + 1];
        z5 = trig[(l * NQ + 5) * 2 + 1];
#pragma unroll
        for (int q = 6; q <= 11; ++q) zh[q - 6] = zhalf[l * NQ + q];

        // ---- 1) diagonal data-encoding phase (layout A) --------------------
#pragma unroll
        for (int k = 0; k < PER_T; ++k) psi[k] = cmul(psi[k], eph[k]);

        // ---- 2) RY q3..5 on k bits (q3<->kb2, q4<->kb1, q5<->kb0) ----------
#pragma unroll
        for (int q = 3; q <= 5; ++q) {
            const int kb = (11 - q) - 6;
            float c = tRY[q - 3].x, s = tRY[q - 3].y;
#pragma unroll
            for (int m = 0; m < PER_T / 2; ++m) {
                int k0 = ((m >> kb) << (kb + 1)) | (m & ((1 << kb) - 1));
                int k1 = k0 | (1 << kb);
                float2 a0 = psi[k0], a1 = psi[k1];
                psi[k0] = make_float2(c * a0.x - s * a1.x, c * a0.y - s * a1.y);
                psi[k1] = make_float2(s * a0.x + c * a1.x, s * a0.y + c * a1.y);
            }
        }

        // ---- 3) RY q6..11 on lane bits -------------------------------------
        ry_shfl<32>(psi, lane, tRY[3].x, tRY[3].y);      // q6  xor32
        ry_shfl<16>(psi, lane, tRY[4].x, tRY[4].y);      // q7  xor16
        ry_dpp<8, 0x128>(psi, lane, tRY[5].x, tRY[5].y); // q8  xor8
        ry_shfl<4>(psi, lane, tRY[6].x, tRY[6].y);       // q9  xor4
        ry_dpp<2, 0x4E>(psi, lane, tRY[7].x, tRY[7].y);  // q10 xor2
        ry_dpp<1, 0xB1>(psi, lane, tRY[8].x, tRY[8].y);  // q11 xor1

        // ---- 4) fused RZ diagonal for q3..11 -------------------------------
        float s_lane = 0.0f;
#pragma unroll
        for (int p = 0; p < 6; ++p)          // lane bit p -> qubit 11-p -> zh[5-p]
            s_lane += ((lane >> p) & 1) ? zh[5 - p] : -zh[5 - p];
        {
            float2 base = fsincos(s_lane);
            float2 z45[4];
#pragma unroll
            for (int c2 = 0; c2 < 4; ++c2) {
                float2 a4 = (c2 & 2) ? z4 : cconj(z4);
                float2 a5 = (c2 & 1) ? z5 : cconj(z5);
                z45[c2] = cmul(a4, a5);
            }
#pragma unroll
            for (int k = 0; k < PER_T; ++k) {
                float2 a3 = (k & 4) ? z3 : cconj(z3);
                float2 ph = cmul(cmul(base, a3), z45[k & 3]);
                psi[k] = cmul(psi[k], ph);
            }
        }

        // ---- 5) pass 1: transpose A -> B (q0-2 become k bits) --------------
#pragma unroll
        for (int k = 0; k < PER_T; ++k) sP[iA[k]] = psi[k];
        __syncthreads();
#pragma unroll
        for (int k = 0; k < PER_T; ++k) psi[k] = sP[iB[k]];

        // ---- 6) RY+RZ q0..2 on k bits (q0<->kb2, q1<->kb1, q2<->kb0) -------
#pragma unroll
        for (int q = 0; q < 3; ++q) {
            const int kb = 2 - q;
            float c = tRY0[q].x, s = tRY0[q].y;
            float2 z = tZ0[q];
#pragma unroll
            for (int m = 0; m < PER_T / 2; ++m) {
                int k0 = ((m >> kb) << (kb + 1)) | (m & ((1 << kb) - 1));
                int k1 = k0 | (1 << kb);
                float2 a0 = psi[k0], a1 = psi[k1];
                float2 n0 = make_float2(c * a0.x - s * a1.x, c * a0.y - s * a1.y);
                float2 n1 = make_float2(s * a0.x + c * a1.x, s * a0.y + c * a1.y);
                psi[k0] = cmul(n0, cconj(z));
                psi[k1] = cmul(n1, z);
            }
        }

        // ---- 7) pass 2: CX ladder + transpose B -> A -----------------------
        // Stage at own global index (iB is what we hold); read g(j) to land
        // the next layer's layout-A set. Pure permutation, no arithmetic.
#pragma unroll
        for (int k = 0; k < PER_T; ++k) sQ[iB[k]] = psi[k];
        __syncthreads();
#pragma unroll
        for (int k = 0; k < PER_T; ++k) psi[k] = sQ[gI[k]];
        // Buffer safety: sP reads(l) precede barrier2(l) < sP writes(l+1);
        // sQ reads(l) precede barrier1(l+1) < sQ writes(l+1).
    }

    // ---- <Z(0)>: qubit 0 = bit 11 = wv bit 2 ------------------------------
    float acc = 0.0f;
#pragma unroll
    for (int k = 0; k < PER_T; ++k)
        acc += psi[k].x * psi[k].x + psi[k].y * psi[k].y;
    if (wv >= 4) acc = -acc;
#pragma unroll
    for (int off = 32; off > 0; off >>= 1)
        acc += __shfl_down(acc, off, 64);
    if (lane == 0) rbuf[wv] = acc;
    __syncthreads();
    if (t == 0) {
        float tot = 0.0f;
#pragma unroll
        for (int i = 0; i < 8; ++i) tot += rbuf[i];
        out[b] = tot;
    }
}

extern "C" void kernel_launch(void* const* d_in, const int* in_sizes, int n_in,
                              void* d_out, int out_size, void* d_ws, size_t ws_size,
                              hipStream_t stream) {
    const float* x = (const float*)d_in[0];   // (256, 12)
    const float* w = (const float*)d_in[1];   // (96,)
    float* out = (float*)d_out;               // (256, 1)
    qcp_kernel<<<BATCH, BLOCK, 0, stream>>>(x, w, out);
}

// Round 12
// 68.884 us; speedup vs baseline: 1.0834x; 1.0294x over previous
//
#include <hip/hip_runtime.h>

#define NQ 12
#define NL 4
#define DIM 4096
#define BLOCK 512
#define PER_T 8           // amplitudes per thread
#define BATCH 256

// Layout A: i = lane | k<<6 | wv<<9   (lane: q6-11, k: q3-5, wv: q0-2)
// Layout B: i = lane | wv<<6 | k<<9   (lane: q6-11, wv: q3-5, k: q0-2)
// Qubit q lives at bit position 11-q of the global amplitude index.
//
// Per layer:
//   regs (layout A): encoding diag, RY q3-5 (k), RY q8-11 (DPP), RZ diag
//     for q3-5 & q8-11;
//   pass1: stage iA -> barrier -> 2-pt gather over bit5 = RY+RZ(q6) fused
//     with the A->B transpose;
//   regs (layout B): RY+RZ q0-2 (k bits);
//   pass2: stage iB -> barrier -> 2-pt gather over bit4 of g(j) = RY+RZ(q7),
//     then CX ladder via the Gray-map g(j)=j^(j>>1) addressing (free).
// Zero ds_bpermute ops; DS traffic = 48 b64 ops/thread/layer (was 80 mixed).
// All gather address sets are lane-bijective maps of contiguous 64-blocks
// -> max 2 lanes/bank (free on gfx950).

__device__ __forceinline__ float2 cmul(float2 a, float2 b) {
    return make_float2(a.x * b.x - a.y * b.y, a.x * b.y + a.y * b.x);
}
__device__ __forceinline__ float2 cconj(float2 a) { return make_float2(a.x, -a.y); }

// HW sincos (revolutions, fract-reduced); |err| ~1e-6 << 1.37e-2 threshold.
__device__ __forceinline__ float2 fsincos(float ang) {   // (cos, sin)
    float r = ang * 0.15915494309189535f;
    r = r - floorf(r);
    return make_float2(__builtin_amdgcn_cosf(r), __builtin_amdgcn_sinf(r));
}

// ---- DPP lane exchanges (VALU pipe, intrinsic-only; no inline asm) --------
// quad_perm xor1 = 0xB1, xor2 = 0x4E, xor3 = 0x1B; row_ror:8 = xor8 = 0x128;
// row_half_mirror = xor7 = 0x141.  xor4 = 0x141 then 0x1B.
template <int CTRL>
__device__ __forceinline__ float dppx(float v) {
    int i = __builtin_bit_cast(int, v);
    int r = __builtin_amdgcn_update_dpp(0, i, CTRL, 0xF, 0xF, true);
    return __builtin_bit_cast(float, r);
}
template <int MSK, int CTRL>
__device__ __forceinline__ void ry_dpp(float2* psi, int lane, float c, float s) {
    const float se = (lane & MSK) ? s : -s;
#pragma unroll
    for (int k = 0; k < PER_T; ++k) {
        float px = dppx<CTRL>(psi[k].x);
        float py = dppx<CTRL>(psi[k].y);
        psi[k].x = c * psi[k].x + se * px;
        psi[k].y = c * psi[k].y + se * py;
    }
}
__device__ __forceinline__ void ry_dpp4(float2* psi, int lane, float c, float s) {
    const float se = (lane & 4) ? s : -s;
#pragma unroll
    for (int k = 0; k < PER_T; ++k) {
        float px = dppx<0x1B>(dppx<0x141>(psi[k].x));
        float py = dppx<0x1B>(dppx<0x141>(psi[k].y));
        psi[k].x = c * psi[k].x + se * px;
        psi[k].y = c * psi[k].y + se * py;
    }
}

__global__ __launch_bounds__(BLOCK, 2) void qcp_kernel(
    const float* __restrict__ x,      // (BATCH, NQ)
    const float* __restrict__ w,      // (NL, NQ, 2) flat: [ry, rz] -> 96
    float* __restrict__ out)          // (BATCH,)
{
    __shared__ float2 sP[DIM];             // pass-1 staging
    __shared__ float2 sQ[DIM];             // pass-2 staging
    __shared__ float2 trig[NL * NQ * 2];   // (cos, sin) of 0.5*w[idx]
    __shared__ float  zhalf[NL * NQ];      // 0.5 * rz weight
    __shared__ float  rbuf[8];

    const int b    = blockIdx.x;
    const int t    = threadIdx.x;
    const int lane = t & 63;
    const int wv   = t >> 6;               // 0..7

    if (t < NL * NQ * 2) trig[t] = fsincos(0.5f * w[t]);
    if (t < NL * NQ) zhalf[t] = 0.5f * w[2 * t + 1];

    float xr[NQ];
#pragma unroll
    for (int q = 0; q < NQ; ++q) xr[q] = x[b * NQ + q];

    // Thread-constant addresses.
    int iA[PER_T], iB[PER_T], gI[PER_T];
#pragma unroll
    for (int k = 0; k < PER_T; ++k) {
        iA[k] = lane | (k << 6) | (wv << 9);
        iB[k] = lane | (wv << 6) | (k << 9);
        gI[k] = iA[k] ^ (iA[k] >> 1);
    }

    // Data-encoding phasors for the layout-A set (identical each layer).
    float2 eph[PER_T];
#pragma unroll
    for (int k = 0; k < PER_T; ++k) {
        int j = iA[k];
        float ang = 0.0f;
#pragma unroll
        for (int q = 0; q < NQ; ++q)
            ang += ((j >> (NQ - 1 - q)) & 1) ? 0.5f * xr[q] : -0.5f * xr[q];
        eph[k] = fsincos(ang);
    }

    float2 psi[PER_T];
#pragma unroll
    for (int k = 0; k < PER_T; ++k) psi[k] = make_float2(0.015625f, 0.0f);

    __syncthreads();   // trig/zhalf ready

    for (int l = 0; l < NL; ++l) {
        // ---- 0) layer coefficients -----------------------------------------
        float2 tRY[9];          // RY (c,s) for q=3..11
        float2 tRY0[3], tZ0[3]; // q=0..2 RY and RZ pairs
        float  zh[4];           // 0.5*rz for q=8..11 (zh[i] = q8+i)
        float2 z3, z4, z5;      // e^{i*0.5*rz} for q=3..5
        float2 z6, z7;          // e^{i*0.5*rz} for q=6, q=7 (fold phases)
#pragma unroll
        for (int q = 3; q <= 11; ++q) tRY[q - 3] = trig[(l * NQ + q) * 2];
#pragma unroll
        for (int q = 0; q < 3; ++q) {
            tRY0[q] = trig[(l * NQ + q) * 2 + 0];
            tZ0[q]  = trig[(l * NQ + q) * 2 + 1];
        }
        z3 = trig[(l * NQ + 3) * 2 + 1];
        z4 = trig[(l * NQ + 4) * 2 + 1];
        z5 = trig[(l * NQ + 5) * 2 + 1];
        z6 = trig[(l * NQ + 6) * 2 + 1];
        z7 = trig[(l * NQ + 7) * 2 + 1];
#pragma unroll
        for (int q = 8; q <= 11; ++q) zh[q - 8] = zhalf[l * NQ + q];

        // ---- 1) diagonal data-encoding phase (layout A) --------------------
#pragma unroll
        for (int k = 0; k < PER_T; ++k) psi[k] = cmul(psi[k], eph[k]);

        // ---- 2) RY q3..5 on k bits (q3<->kb2, q4<->kb1, q5<->kb0) ----------
#pragma unroll
        for (int q = 3; q <= 5; ++q) {
            const int kb = (11 - q) - 6;
            float c = tRY[q - 3].x, s = tRY[q - 3].y;
#pragma unroll
            for (int m = 0; m < PER_T / 2; ++m) {
                int k0 = ((m >> kb) << (kb + 1)) | (m & ((1 << kb) - 1));
                int k1 = k0 | (1 << kb);
                float2 a0 = psi[k0], a1 = psi[k1];
                psi[k0] = make_float2(c * a0.x - s * a1.x, c * a0.y - s * a1.y);
                psi[k1] = make_float2(s * a0.x + c * a1.x, s * a0.y + c * a1.y);
            }
        }

        // ---- 3) RY q8..11 on lane bits (DPP only) --------------------------
        ry_dpp<8, 0x128>(psi, lane, tRY[5].x, tRY[5].y); // q8  xor8
        ry_dpp4(psi, lane, tRY[6].x, tRY[6].y);          // q9  xor4
        ry_dpp<2, 0x4E>(psi, lane, tRY[7].x, tRY[7].y);  // q10 xor2
        ry_dpp<1, 0xB1>(psi, lane, tRY[8].x, tRY[8].y);  // q11 xor1

        // ---- 4) fused RZ diagonal for q3..5 and q8..11 ---------------------
        // (q6,q7 RZs ride inside the pass folds, after their RYs.)
        float s_lane = 0.0f;
#pragma unroll
        for (int p = 0; p < 4; ++p)          // lane bit p -> qubit 11-p -> zh[3-p]
            s_lane += ((lane >> p) & 1) ? zh[3 - p] : -zh[3 - p];
        {
            float2 base = fsincos(s_lane);
            float2 z45[4];
#pragma unroll
            for (int c2 = 0; c2 < 4; ++c2) {
                float2 a4 = (c2 & 2) ? z4 : cconj(z4);
                float2 a5 = (c2 & 1) ? z5 : cconj(z5);
                z45[c2] = cmul(a4, a5);
            }
#pragma unroll
            for (int k = 0; k < PER_T; ++k) {
                float2 a3 = (k & 4) ? z3 : cconj(z3);
                float2 ph = cmul(cmul(base, a3), z45[k & 3]);
                psi[k] = cmul(psi[k], ph);
            }
        }

        // ---- 5) pass 1: A -> B transpose fused with RY+RZ(q6) --------------
        // target bit5 = lane bit5 (identical in both layouts).
#pragma unroll
        for (int k = 0; k < PER_T; ++k) sP[iA[k]] = psi[k];

        const int  b6  = (lane >> 5) & 1;
        const float c6 = tRY[3].x;
        const float se6 = b6 ? tRY[3].y : -tRY[3].y;
        const float2 zb6 = b6 ? z6 : cconj(z6);
        __syncthreads();
#pragma unroll
        for (int k = 0; k < PER_T; ++k) {
            float2 own = sP[iB[k]];
            float2 oth = sP[iB[k] ^ 32];
            float2 n = make_float2(c6 * own.x + se6 * oth.x,
                                   c6 * own.y + se6 * oth.y);
            psi[k] = cmul(n, zb6);
        }

        // ---- 6) RY+RZ q0..2 on k bits (q0<->kb2, q1<->kb1, q2<->kb0) -------
#pragma unroll
        for (int q = 0; q < 3; ++q) {
            const int kb = 2 - q;
            float c = tRY0[q].x, s = tRY0[q].y;
            float2 z = tZ0[q];
#pragma unroll
            for (int m = 0; m < PER_T / 2; ++m) {
                int k0 = ((m >> kb) << (kb + 1)) | (m & ((1 << kb) - 1));
                int k1 = k0 | (1 << kb);
                float2 a0 = psi[k0], a1 = psi[k1];
                float2 n0 = make_float2(c * a0.x - s * a1.x, c * a0.y - s * a1.y);
                float2 n1 = make_float2(s * a0.x + c * a1.x, s * a0.y + c * a1.y);
                psi[k0] = cmul(n0, cconj(z));
                psi[k1] = cmul(n1, z);
            }
        }

        // ---- 7) pass 2: RY+RZ(q7) + CX ladder + B -> A ---------------------
        // new[j] = zb7 * (c7*staged[g(j)] + se7*staged[g(j)^16]);
        // row bit = bit4 of g(j) = lane4 ^ lane5 (thread-uniform).
#pragma unroll
        for (int k = 0; k < PER_T; ++k) sQ[iB[k]] = psi[k];

        const int  b7  = ((lane >> 4) ^ (lane >> 5)) & 1;
        const float c7 = tRY[4].x;
        const float se7 = b7 ? tRY[4].y : -tRY[4].y;
        const float2 zb7 = b7 ? z7 : cconj(z7);
        __syncthreads();
#pragma unroll
        for (int k = 0; k < PER_T; ++k) {
            float2 own = sQ[gI[k]];
            float2 oth = sQ[gI[k] ^ 16];
            float2 n = make_float2(c7 * own.x + se7 * oth.x,
                                   c7 * own.y + se7 * oth.y);
            psi[k] = cmul(n, zb7);
        }
        // Buffer safety: sP reads(l) precede barrier2(l) < sP writes(l+1);
        // sQ reads(l) precede barrier1(l+1) < sQ writes(l+1).
    }

    // ---- <Z(0)>: qubit 0 = bit 11 = wv bit 2 ------------------------------
    float acc = 0.0f;
#pragma unroll
    for (int k = 0; k < PER_T; ++k)
        acc += psi[k].x * psi[k].x + psi[k].y * psi[k].y;
    if (wv >= 4) acc = -acc;
#pragma unroll
    for (int off = 32; off > 0; off >>= 1)
        acc += __shfl_down(acc, off, 64);
    if (lane == 0) rbuf[wv] = acc;
    __syncthreads();
    if (t == 0) {
        float tot = 0.0f;
#pragma unroll
        for (int i = 0; i < 8; ++i) tot += rbuf[i];
        out[b] = tot;
    }
}

extern "C" void kernel_launch(void* const* d_in, const int* in_sizes, int n_in,
                              void* d_out, int out_size, void* d_ws, size_t ws_size,
                              hipStream_t stream) {
    const float* x = (const float*)d_in[0];   // (256, 12)
    const float* w = (const float*)d_in[1];   // (96,)
    float* out = (float*)d_out;               // (256, 1)
    qcp_kernel<<<BATCH, BLOCK, 0, stream>>>(x, w, out);
}